// Round 8
// baseline (284.271 us; speedup 1.0000x reference)
//
#include <hip/hip_runtime.h>

// B=8, C=16, H=W=384. Inputs (fp32): net_out, target, max_positiones.
// loss_bc = 0.05*m1/(d1+eps) + 0.95*m2/(d2+eps)
//   m1 = sum(d2*t), d1 = sum(t), m2 = sum(d2) - m1, d2den = HW - d1
// active_bc = !(max(t)==0 && max(mp)==0) -> mp scanned only if max(t)==0 (rare path)
// img_loss_b = sum_c(losses)/count_nonzero(losses); out = mean_b.
//
// R8: R6's register-nt geometry (the established read-ceiling config:
// ~5.5 B/cy/CU read-return with NT; passA ~45us = 151MB @ 3.36 TB/s) with
// the 1-block final kernel FUSED via last-block-done (partials ->
// threadfence -> atomicAdd ticket; last block fences + finalizes).
// Saves one dispatch + ~5us. Ticket zeroed by a 4B hipMemsetAsync
// (graph-capture-safe; harness itself uses memsetAsync).

typedef float f32x4 __attribute__((ext_vector_type(4)));

#define B_DIM 8
#define C_DIM 16
#define BC    (B_DIM * C_DIM)        // 128
#define HW    147456                 // 384*384
#define SEGS  16
#define SEG_ELEMS (HW / SEGS)        // 9216
#define TPB   256
#define F4PT  (SEG_ELEMS / 4 / TPB)  // 9 float4 per thread per array
#define NBLK  (BC * SEGS)            // 2048

#define ALPHA  0.05f
#define SMOOTH 1e-6f

// ws layout: NBLK float4 partials {sum_t, m1, sum_d2, mx_t}, then uint ticket.

__global__ __launch_bounds__(TPB, 2) void mismatch_fused(
    const float* __restrict__ net_out,
    const float* __restrict__ target,
    const float* __restrict__ maxp,
    float4* __restrict__ ws,
    unsigned int* __restrict__ ticket,
    float* __restrict__ out)
{
    const int blk = blockIdx.x;                       // [0, NBLK)
    const size_t base4 = (size_t)blk * (SEG_ELEMS / 4);
    const int tid = threadIdx.x;

    const f32x4* __restrict__ t4 = (const f32x4*)target + base4;
    const f32x4* __restrict__ n4 = (const f32x4*)net_out + base4;

    float sum_t = 0.f, m1 = 0.f, sd2 = 0.f, mxt = 0.f;

#pragma unroll
    for (int k = 0; k < F4PT; ++k) {
        const int idx = k * TPB + tid;   // coalesced float4, nt (no L1/L2 alloc)
        const f32x4 tv = __builtin_nontemporal_load(t4 + idx);
        const f32x4 nv = __builtin_nontemporal_load(n4 + idx);
#define ACC(c) { float t = tv.c, n = nv.c;                \
                 float d = t - n; float d2 = d * d;       \
                 sum_t += t; sd2 += d2;                   \
                 m1 = fmaf(d2, t, m1); mxt = fmaxf(mxt, t); }
        ACC(x) ACC(y) ACC(z) ACC(w)
#undef ACC
    }

    // wave (64-lane) reduction
#pragma unroll
    for (int off = 32; off > 0; off >>= 1) {
        sum_t += __shfl_down(sum_t, off);
        m1    += __shfl_down(m1, off);
        sd2   += __shfl_down(sd2, off);
        mxt    = fmaxf(mxt, __shfl_down(mxt, off));
    }

    __shared__ float s[4][4];
    __shared__ int is_last;
    const int wave = tid >> 6, lane = tid & 63;
    if (lane == 0) { s[wave][0] = sum_t; s[wave][1] = m1; s[wave][2] = sd2; s[wave][3] = mxt; }
    __syncthreads();
    if (tid == 0) {
        float4 o;
        o.x = s[0][0] + s[1][0] + s[2][0] + s[3][0];
        o.y = s[0][1] + s[1][1] + s[2][1] + s[3][1];
        o.z = s[0][2] + s[1][2] + s[2][2] + s[3][2];
        o.w = fmaxf(fmaxf(s[0][3], s[1][3]), fmaxf(s[2][3], s[3][3]));
        ws[blk] = o;
        __threadfence();                               // publish partial (device scope)
        const unsigned int old = atomicAdd(ticket, 1u);  // device-scope by default
        is_last = (old == NBLK - 1) ? 1 : 0;
    }
    __syncthreads();
    if (!is_last) return;

    // ---- finalize (exactly one block reaches here) ----
    __threadfence();   // acquire: invalidate L1 so partials from other XCDs are fresh

    __shared__ float losses[BC];
    __shared__ float img[B_DIM];

    if (tid < BC) {    // one thread per (b,c) slice
        float a = 0.f, b = 0.f, c = 0.f, mt = 0.f;
#pragma unroll
        for (int g = 0; g < SEGS; ++g) {
            const float4 v = ws[(tid << 4) + g];
            a += v.x; b += v.y; c += v.z; mt = fmaxf(mt, v.w);
        }
        bool inactive = false;
        if (mt == 0.f) {
            // Rare path: slice's target all-zero; must consult max_positiones.
            const float4* m4 = (const float4*)maxp + (size_t)tid * (HW / 4);
            float mx = 0.f;
            for (int i = 0; i < HW / 4; ++i) {
                const float4 v = m4[i];
                mx = fmaxf(mx, fmaxf(fmaxf(v.x, v.y), fmaxf(v.z, v.w)));
            }
            inactive = (mx == 0.f);
        }
        const float m2v = c - b;
        const float loss = ALPHA * b / (a + SMOOTH)
                         + (1.f - ALPHA) * m2v / ((float)HW - a + SMOOTH);
        losses[tid] = inactive ? 0.f : loss;
    }
    __syncthreads();
    if (tid < B_DIM) {
        float sm = 0.f; int cnt = 0;
#pragma unroll
        for (int c = 0; c < C_DIM; ++c) {
            const float l = losses[tid * C_DIM + c];
            sm += l;
            cnt += (l != 0.f) ? 1 : 0;
        }
        img[tid] = sm / (float)cnt;   // 0/0 -> NaN matches reference
    }
    __syncthreads();
    if (tid == 0) {
        float sm = 0.f;
#pragma unroll
        for (int b = 0; b < B_DIM; ++b) sm += img[b];
        out[0] = sm / (float)B_DIM;
    }
}

extern "C" void kernel_launch(void* const* d_in, const int* in_sizes, int n_in,
                              void* d_out, int out_size, void* d_ws, size_t ws_size,
                              hipStream_t stream) {
    const float* net_out = (const float*)d_in[0];
    const float* target  = (const float*)d_in[1];
    const float* maxp    = (const float*)d_in[2];
    float* out = (float*)d_out;
    float4* ws = (float4*)d_ws;                      // NBLK*16 = 32 KB partials
    unsigned int* ticket = (unsigned int*)((char*)d_ws + (size_t)NBLK * sizeof(float4));

    hipMemsetAsync(ticket, 0, sizeof(unsigned int), stream);  // graph-capture-safe
    mismatch_fused<<<NBLK, TPB, 0, stream>>>(net_out, target, maxp, ws, ticket, out);
}